// Round 10
// baseline (677.333 us; speedup 1.0000x reference)
//
#include <hip/hip_runtime.h>
#include <stdint.h>

#define NIMG 32
#define CH 32
#define HH 160
#define WW 160
#define HWL (HH*WW)            // 25600
#define PRS 164                // padded row stride (words)
#define PHH 162
#define PIMG (PHH*PRS)         // 26568 words per padded image
#define NPIX (NIMG*HWL)        // 819200 pixels
#define HALO_WORDS 968         // per image: 2*164 + 160*4
#define NBLK 800

// workspace layout (bytes)
#define OFF_P     0
#define OFF_P2    3400704                    // P : 32*26568*4
#define OFF_WP    (OFF_P2 + 3400704)
#define OFF_CORR  (OFF_WP + 2304)
#define OFF_SC    (OFF_CORR + 2304)
#define OFF_SB    (OFF_SC + 128)             // 64 StatLines x 128 B
#define OFF_CNT   (OFF_SB + 8192)            // 4 barrier counters

struct StatLine {                            // one 128B line per channel
  int s1; int pad0; unsigned long long s2; char pad[112];
};

#define AS1 __attribute__((address_space(1)))
#define AS3 __attribute__((address_space(3)))
__device__ __forceinline__ void dma16(const void* g, void* l) {
  __builtin_amdgcn_global_load_lds((const AS1 void*)g, (AS3 void*)l, 16, 0, 0);
}

__device__ __forceinline__ unsigned short f2bf(float f) {   // RNE float->bf16
  unsigned u = __float_as_uint(f);
  u += 0x7fffu + ((u >> 16) & 1u);
  return (unsigned short)(u >> 16);
}
__device__ __forceinline__ float bf2f(unsigned short u) {
  return __uint_as_float((uint32_t)u << 16);
}

__device__ __forceinline__ void conv4(const uint32_t r[3][6], const uint32_t* wsh,
                                      int co, int& a0, int& a1, int& a2, int& a3)
{
  a0 = a1 = a2 = a3 = 0;
  #pragma unroll
  for (int dy = 0; dy < 3; ++dy) {
    #pragma unroll
    for (int dx = 0; dx < 3; ++dx) {
      uint32_t wvv = wsh[co * 9 + dy * 3 + dx];
      a0 += __popc(r[dy][0 + dx] ^ wvv);
      a1 += __popc(r[dy][1 + dx] ^ wvv);
      a2 += __popc(r[dy][2 + dx] ^ wvv);
      a3 += __popc(r[dy][3 + dx] ^ wvv);
    }
  }
}

// device-scope grid barrier; all NBLK blocks are co-resident by construction
// (128 VGPR cap + 35 KB LDS -> 4 blocks/CU -> capacity 1024 >= 800)
__device__ __forceinline__ void gridbar(int* cnt) {
  __syncthreads();                            // drains each wave's vmcnt too
  if (threadIdx.x == 0) {
    __threadfence();                          // flush XCD-L2 to coherent point
    atomicAdd(cnt, 1);                        // device-scope by default (m20)
    int it = 0;
    while (__hip_atomic_load(cnt, __ATOMIC_ACQUIRE, __HIP_MEMORY_SCOPE_AGENT) < NBLK) {
      __builtin_amdgcn_s_sleep(16);
      if (++it > (1 << 28)) break;            // safety valve
    }
    __threadfence();
  }
  __syncthreads();
}

__global__ __launch_bounds__(256, 4) void mega(
    const float* __restrict__ x,
    const float* __restrict__ w1, const float* __restrict__ g1, const float* __restrict__ b1,
    const float* __restrict__ w2, const float* __restrict__ g2, const float* __restrict__ b2,
    uint32_t* __restrict__ P, uint32_t* __restrict__ P2,
    uint32_t* __restrict__ WP, int* __restrict__ CORR, float* __restrict__ SC,
    StatLine* __restrict__ SB, int* __restrict__ cnt, float* __restrict__ out)
{
  __shared__ float lds[8192];                // 32 KB: pack stage / prep scratch / ls
  __shared__ uint32_t wsh[288];
  __shared__ int csh[288];
  __shared__ float Ash[32], Bsh[32];
  const int tid = threadIdx.x;
  const int b = blockIdx.x;

  // ---------------- phase 0a: halo zero (blocks 0..241, exactly 61952 words)
  if (b < 242) {
    int k = b * 256 + tid;
    uint32_t* buf = (k < 32 * HALO_WORDS) ? P : P2;
    int j = k % (32 * HALO_WORDS);
    int img = j / HALO_WORDS;
    int r = j - img * HALO_WORDS;
    int pr, pc;
    if (r < 164)      { pr = 0;   pc = r; }
    else if (r < 328) { pr = 161; pc = r - 164; }
    else {
      int k2 = r - 328;
      pr = 1 + (k2 >> 2);
      int q = k2 & 3;
      pc = (q == 0) ? 0 : (160 + q);
    }
    buf[img * PIMG + pr * PRS + pc] = 0;
  }

  // ---------------- phase 0b: pack own 1024 px (4 subtiles x 256 px, DMA staged)
  {
    int n = b / 25;
    int base_px = (b - n * 25) * 1024;
    for (int s = 0; s < 4; ++s) {
      int p0 = base_px + s * 256;
      const float* xb = x + (size_t)n * CH * HWL + p0;
      #pragma unroll
      for (int it = 0; it < 8; ++it) {
        int c = it * 4 + (tid >> 6);         // wave-uniform channel
        dma16(xb + (size_t)c * HWL + (tid & 63) * 4, lds + c * 256);
      }
      __syncthreads();                        // DMA drained -> tile ready
      uint32_t bits = 0;
      #pragma unroll
      for (int c = 0; c < 32; ++c)
        if (lds[c * 256 + tid] > 0.f) bits |= 1u << c;
      int px = p0 + tid;
      int h = px / WW, w = px - (px / WW) * WW;
      P[n * PIMG + (h + 1) * PRS + (w + 1)] = bits;
      __syncthreads();                        // WAR before next subtile DMA
    }
  }

  // ---------------- phase 0c: prep (block 799)
  if (b == NBLK - 1) {
    int* z = (int*)SB;
    for (int i = tid; i < 2048; i += 256) z[i] = 0;
    float* red = lds;
    uint32_t* wpl = (uint32_t*)(lds + 256);
    for (int cv = 0; cv < 2; ++cv) {
      const float* w = cv ? w2 : w1;
      float s = 0.f;
      #pragma unroll
      for (int j = 0; j < 9; ++j) {
        float4 v = *reinterpret_cast<const float4*>(w + (j * 256 + tid) * 4);
        s += fabsf(v.x) + fabsf(v.y) + fabsf(v.z) + fabsf(v.w);
      }
      red[tid] = s;
      __syncthreads();
      for (int st = 128; st > 0; st >>= 1) {
        if (tid < st) red[tid] += red[tid + st];
        __syncthreads();
      }
      if (tid == 0) SC[cv] = red[0] / 9216.0f;
      for (int i = tid; i < 288; i += 256) {
        int co = i / 9, t = i - co * 9;
        uint32_t bw = 0;
        for (int ci = 0; ci < 32; ++ci)
          bw |= (w[(co * 32 + ci) * 9 + t] > 0.0f) ? (1u << ci) : 0u;
        WP[cv * 288 + i] = bw;
        wpl[i] = bw;
      }
      __syncthreads();
      for (int i = tid; i < 288; i += 256) {
        int cls = i / 32, co = i - cls * 32;
        int hc = cls / 3, wc = cls - hc * 3;
        int corr = 0;
        for (int t = 0; t < 9; ++t) {
          int dy = t / 3 - 1, dx = t % 3 - 1;
          bool inval = (hc == 0 && dy == -1) || (hc == 2 && dy == 1) ||
                       (wc == 0 && dx == -1) || (wc == 2 && dx == 1);
          if (inval) corr += 32 - 2 * __popc(wpl[co * 9 + t]);
        }
        CORR[cv * 288 + cls * 32 + co] = corr;
      }
      __syncthreads();
    }
  }

  gridbar(cnt + 0);

  // ---------------- conv pixel mapping, fixed for phases 1-4
  int g = b * 256 + tid;                      // over 32*160*40 quad-columns
  int w4 = g % 40;
  int t1 = g / 40;
  int h = t1 % 160;
  int n2 = t1 / 160;
  int rowc = (h == 0) ? 0 : ((h == 159) ? 6 : 3);
  int cls0  = rowc + ((w4 == 0) ? 0 : 1);
  int cls12 = rowc + 1;
  int cls3  = rowc + ((w4 == 39) ? 2 : 1);
  size_t pbase = (size_t)n2 * CH * HWL + h * WW + w4 * 4;
  int lane = tid & 63;

  int* ls1 = (int*)lds;
  int* ls2 = (int*)lds + 32;
  for (int i = tid; i < 288; i += 256) { wsh[i] = WP[i]; csh[i] = CORR[i]; }
  if (tid < 32) { ls1[tid] = 0; ls2[tid] = 0; }
  __syncthreads();

  uint32_t r[3][6];
  {
    const uint32_t* bp = P + n2 * PIMG + h * PRS + w4 * 4;
    #pragma unroll
    for (int dy = 0; dy < 3; ++dy) {
      uint4 a = *reinterpret_cast<const uint4*>(bp + dy * PRS);
      uint2 bw = *reinterpret_cast<const uint2*>(bp + dy * PRS + 4);
      r[dy][0] = a.x; r[dy][1] = a.y; r[dy][2] = a.z; r[dy][3] = a.w;
      r[dy][4] = bw.x; r[dy][5] = bw.y;
    }
  }

  // ---------------- phase 1: conv1 -> stats1
  #pragma unroll
  for (int co = 0; co < 32; ++co) {
    int a0, a1, a2, a3;
    conv4(r, wsh, co, a0, a1, a2, a3);
    int d0 = 288 - 2 * a0 - csh[cls0 * 32 + co];
    int d1 = 288 - 2 * a1 - csh[cls12 * 32 + co];
    int d2 = 288 - 2 * a2 - csh[cls12 * 32 + co];
    int d3 = 288 - 2 * a3 - csh[cls3 * 32 + co];
    int ds = d0 + d1 + d2 + d3;
    int sq = d0 * d0 + d1 * d1 + d2 * d2 + d3 * d3;
    #pragma unroll
    for (int off = 32; off > 0; off >>= 1) {
      ds += __shfl_down(ds, off);
      sq += __shfl_down(sq, off);
    }
    if (lane == 0) { atomicAdd(&ls1[co], ds); atomicAdd(&ls2[co], sq); }
  }
  __syncthreads();
  if (tid < 32) {
    atomicAdd(&SB[tid].s1, ls1[tid]);
    atomicAdd(&SB[tid].s2, (unsigned long long)(long long)ls2[tid]);
  }

  gridbar(cnt + 1);

  // ---------------- phase 2: bn1 -> inner kept in registers + P2 bits
  if (tid < 32) {
    double sc = (double)SC[0];
    double m  = sc * (double)SB[tid].s1 / (double)NPIX;
    double ms = sc * sc * (double)(long long)SB[tid].s2 / (double)NPIX;
    float inv = (float)(1.0 / sqrt(ms - m * m + 1e-5));
    float gm = g1[tid];
    Ash[tid] = gm * inv * (float)sc;
    Bsh[tid] = b1[tid] - gm * inv * (float)m;
  }
  __syncthreads();

  ushort4 iv[32];                             // inner bf16, 64 VGPRs, lives to phase 4
  uint32_t bb0 = 0, bb1 = 0, bb2 = 0, bb3 = 0;
  #pragma unroll
  for (int cg = 0; cg < 4; ++cg) {
    float4 xv[8];                             // 32 VGPRs in flight per group
    #pragma unroll
    for (int j = 0; j < 8; ++j)
      xv[j] = *reinterpret_cast<const float4*>(x + pbase + (size_t)(cg * 8 + j) * HWL);
    #pragma unroll
    for (int j = 0; j < 8; ++j) {
      int co = cg * 8 + j;
      int a0, a1, a2, a3;
      conv4(r, wsh, co, a0, a1, a2, a3);
      int d0 = 288 - 2 * a0 - csh[cls0 * 32 + co];
      int d1 = 288 - 2 * a1 - csh[cls12 * 32 + co];
      int d2 = 288 - 2 * a2 - csh[cls12 * 32 + co];
      int d3 = 288 - 2 * a3 - csh[cls3 * 32 + co];
      float A = Ash[co], Bv = Bsh[co];
      float v0 = fmaf(A, (float)d0, Bv) + xv[j].x;
      float v1 = fmaf(A, (float)d1, Bv) + xv[j].y;
      float v2 = fmaf(A, (float)d2, Bv) + xv[j].z;
      float v3 = fmaf(A, (float)d3, Bv) + xv[j].w;
      ushort4 o; o.x = f2bf(v0); o.y = f2bf(v1); o.z = f2bf(v2); o.w = f2bf(v3);
      iv[co] = o;
      uint32_t m = 1u << co;
      if (v0 > 0.f) bb0 |= m;
      if (v1 > 0.f) bb1 |= m;
      if (v2 > 0.f) bb2 |= m;
      if (v3 > 0.f) bb3 |= m;
    }
  }
  {
    uint32_t* pw = P2 + n2 * PIMG + (h + 1) * PRS + (w4 * 4 + 1);
    pw[0] = bb0; pw[1] = bb1; pw[2] = bb2; pw[3] = bb3;
  }

  gridbar(cnt + 2);

  // ---------------- phase 3: conv2 -> stats2
  for (int i = tid; i < 288; i += 256) { wsh[i] = WP[288 + i]; csh[i] = CORR[288 + i]; }
  if (tid < 32) { ls1[tid] = 0; ls2[tid] = 0; }
  __syncthreads();
  {
    const uint32_t* bp = P2 + n2 * PIMG + h * PRS + w4 * 4;
    #pragma unroll
    for (int dy = 0; dy < 3; ++dy) {
      uint4 a = *reinterpret_cast<const uint4*>(bp + dy * PRS);
      uint2 bw = *reinterpret_cast<const uint2*>(bp + dy * PRS + 4);
      r[dy][0] = a.x; r[dy][1] = a.y; r[dy][2] = a.z; r[dy][3] = a.w;
      r[dy][4] = bw.x; r[dy][5] = bw.y;
    }
  }
  #pragma unroll
  for (int co = 0; co < 32; ++co) {
    int a0, a1, a2, a3;
    conv4(r, wsh, co, a0, a1, a2, a3);
    int d0 = 288 - 2 * a0 - csh[cls0 * 32 + co];
    int d1 = 288 - 2 * a1 - csh[cls12 * 32 + co];
    int d2 = 288 - 2 * a2 - csh[cls12 * 32 + co];
    int d3 = 288 - 2 * a3 - csh[cls3 * 32 + co];
    int ds = d0 + d1 + d2 + d3;
    int sq = d0 * d0 + d1 * d1 + d2 * d2 + d3 * d3;
    #pragma unroll
    for (int off = 32; off > 0; off >>= 1) {
      ds += __shfl_down(ds, off);
      sq += __shfl_down(sq, off);
    }
    if (lane == 0) { atomicAdd(&ls1[co], ds); atomicAdd(&ls2[co], sq); }
  }
  __syncthreads();
  if (tid < 32) {
    atomicAdd(&SB[32 + tid].s1, ls1[tid]);
    atomicAdd(&SB[32 + tid].s2, (unsigned long long)(long long)ls2[tid]);
  }

  gridbar(cnt + 3);

  // ---------------- phase 4: bn2 + residual(registers) -> out
  if (tid < 32) {
    double sc = (double)SC[1];
    double m  = sc * (double)SB[32 + tid].s1 / (double)NPIX;
    double ms = sc * sc * (double)(long long)SB[32 + tid].s2 / (double)NPIX;
    float inv = (float)(1.0 / sqrt(ms - m * m + 1e-5));
    float gm = g2[tid];
    Ash[tid] = gm * inv * (float)sc;
    Bsh[tid] = b2[tid] - gm * inv * (float)m;
  }
  __syncthreads();

  #pragma unroll
  for (int co = 0; co < 32; ++co) {
    int a0, a1, a2, a3;
    conv4(r, wsh, co, a0, a1, a2, a3);
    int d0 = 288 - 2 * a0 - csh[cls0 * 32 + co];
    int d1 = 288 - 2 * a1 - csh[cls12 * 32 + co];
    int d2 = 288 - 2 * a2 - csh[cls12 * 32 + co];
    int d3 = 288 - 2 * a3 - csh[cls3 * 32 + co];
    float A = Ash[co], Bv = Bsh[co];
    float4 o;
    o.x = fmaf(A, (float)d0, Bv) + bf2f(iv[co].x);
    o.y = fmaf(A, (float)d1, Bv) + bf2f(iv[co].y);
    o.z = fmaf(A, (float)d2, Bv) + bf2f(iv[co].z);
    o.w = fmaf(A, (float)d3, Bv) + bf2f(iv[co].w);
    *reinterpret_cast<float4*>(out + pbase + (size_t)co * HWL) = o;
  }
}

extern "C" void kernel_launch(void* const* d_in, const int* in_sizes, int n_in,
                              void* d_out, int out_size, void* d_ws, size_t ws_size,
                              hipStream_t stream)
{
  (void)in_sizes; (void)n_in; (void)out_size; (void)ws_size;
  const float* x  = (const float*)d_in[0];
  const float* w1 = (const float*)d_in[1];
  const float* g1 = (const float*)d_in[2];
  const float* b1 = (const float*)d_in[3];
  const float* w2 = (const float*)d_in[4];
  const float* g2 = (const float*)d_in[5];
  const float* b2 = (const float*)d_in[6];
  float* out = (float*)d_out;
  char* ws = (char*)d_ws;

  uint32_t* P    = (uint32_t*)(ws + OFF_P);
  uint32_t* P2   = (uint32_t*)(ws + OFF_P2);
  uint32_t* WP   = (uint32_t*)(ws + OFF_WP);
  int*      CORR = (int*)(ws + OFF_CORR);
  float*    SC   = (float*)(ws + OFF_SC);
  StatLine* SB   = (StatLine*)(ws + OFF_SB);
  int*      CNT  = (int*)(ws + OFF_CNT);

  hipMemsetAsync(CNT, 0, 4 * sizeof(int), stream);   // barrier counters per launch
  mega<<<NBLK, 256, 0, stream>>>(x, w1, g1, b1, w2, g2, b2,
                                 P, P2, WP, CORR, SC, SB, CNT, out);
}

// Round 11
// 194.715 us; speedup vs baseline: 3.4786x; 3.4786x over previous
//
#include <hip/hip_runtime.h>
#include <stdint.h>

#define NIMG 32
#define CH 32
#define HH 160
#define WW 160
#define HWL (HH*WW)            // 25600
#define PRS 164                // padded row stride (words)
#define PHH 162
#define PIMG (PHH*PRS)         // 26568 words per padded image
#define NPIX (NIMG*HWL)        // 819200 pixels
#define HALO_WORDS 968         // per image: 2*164 + 160*4

// workspace layout (bytes)
#define OFF_P     0
#define OFF_P2    3400704                    // P : 32*26568*4
#define OFF_WP    (OFF_P2 + 3400704)
#define OFF_CORR  (OFF_WP + 2304)
#define OFF_SC    (OFF_CORR + 2304)
#define OFF_SB    (OFF_SC + 128)             // 64 StatLines x 128 B

struct StatLine {                            // one 128B line per channel
  int s1; int pad0; unsigned long long s2; char pad[112];
};

#define AS1 __attribute__((address_space(1)))
#define AS3 __attribute__((address_space(3)))
__device__ __forceinline__ void dma16(const void* g, void* l) {
  __builtin_amdgcn_global_load_lds((const AS1 void*)g, (AS3 void*)l, 16, 0, 0);
}

__device__ __forceinline__ void conv4(const uint32_t r[3][6], const uint32_t* wsh,
                                      int co, int& a0, int& a1, int& a2, int& a3)
{
  a0 = a1 = a2 = a3 = 0;
  #pragma unroll
  for (int dy = 0; dy < 3; ++dy) {
    #pragma unroll
    for (int dx = 0; dx < 3; ++dx) {
      uint32_t wvv = wsh[co * 9 + dy * 3 + dx];
      a0 += __popc(r[dy][0 + dx] ^ wvv);
      a1 += __popc(r[dy][1 + dx] ^ wvv);
      a2 += __popc(r[dy][2 + dx] ^ wvv);
      a3 += __popc(r[dy][3 + dx] ^ wvv);
    }
  }
}

// ================ K1: pack x via LDS DMA staging (256px tile) + prep + halo zero ====
// blocks 0..3199: pack (256 px x 32 ch, 32 KB); 3200..3441: halo zero; 3442: prep
__global__ __launch_bounds__(256) void pack_prep(const float* __restrict__ x,
    const float* __restrict__ w1, const float* __restrict__ w2,
    uint32_t* __restrict__ P, uint32_t* __restrict__ P2, uint32_t* __restrict__ WP,
    int* __restrict__ CORR, float* __restrict__ SC, StatLine* __restrict__ SB)
{
  __shared__ float lds[8192];                // 32 KB
  const int tid = threadIdx.x;
  const int b = blockIdx.x;

  if (b >= 3200) {
    if (b == 3442) {
      // ---- prep: zero stats, weight scale, bit-pack, border corrections
      int* z = (int*)SB;
      for (int i = tid; i < 2048; i += 256) z[i] = 0;
      float* red = lds;                      // 256 floats
      uint32_t* wpl = (uint32_t*)(lds + 256); // 288 words
      for (int cv = 0; cv < 2; ++cv) {
        const float* w = cv ? w2 : w1;
        float s = 0.f;
        #pragma unroll
        for (int j = 0; j < 9; ++j) {
          float4 v = *reinterpret_cast<const float4*>(w + (j * 256 + tid) * 4);
          s += fabsf(v.x) + fabsf(v.y) + fabsf(v.z) + fabsf(v.w);
        }
        red[tid] = s;
        __syncthreads();
        for (int st = 128; st > 0; st >>= 1) {
          if (tid < st) red[tid] += red[tid + st];
          __syncthreads();
        }
        if (tid == 0) SC[cv] = red[0] / 9216.0f;
        for (int i = tid; i < 288; i += 256) {
          int co = i / 9, t = i - co * 9;
          uint32_t bw = 0;
          for (int ci = 0; ci < 32; ++ci)
            bw |= (w[(co * 32 + ci) * 9 + t] > 0.0f) ? (1u << ci) : 0u;
          WP[cv * 288 + i] = bw;
          wpl[i] = bw;
        }
        __syncthreads();
        for (int i = tid; i < 288; i += 256) {
          int cls = i / 32, co = i - cls * 32;
          int hc = cls / 3, wc = cls - hc * 3;
          int corr = 0;
          for (int t = 0; t < 9; ++t) {
            int dy = t / 3 - 1, dx = t % 3 - 1;
            bool inval = (hc == 0 && dy == -1) || (hc == 2 && dy == 1) ||
                         (wc == 0 && dx == -1) || (wc == 2 && dx == 1);
            if (inval) corr += 32 - 2 * __popc(wpl[co * 9 + t]);
          }
          CORR[cv * 288 + cls * 32 + co] = corr;
        }
        __syncthreads();
      }
    } else {
      // ---- halo zero for P and P2: 2*32*968 = 61952 words, blocks 3200..3441
      int k = (b - 3200) * 256 + tid;
      uint32_t* buf = (k < 32 * HALO_WORDS) ? P : P2;
      int j = k % (32 * HALO_WORDS);
      int img = j / HALO_WORDS;
      int r = j - img * HALO_WORDS;
      int pr, pc;
      if (r < 164)      { pr = 0;   pc = r; }
      else if (r < 328) { pr = 161; pc = r - 164; }
      else {
        int k2 = r - 328;
        pr = 1 + (k2 >> 2);
        int q = k2 & 3;
        pc = (q == 0) ? 0 : (160 + q);
      }
      buf[img * PIMG + pr * PRS + pc] = 0;
    }
    return;
  }

  // ---- pack: tile = 256 px x 32 ch staged to LDS [c][256] via 8 DMA/thread
  int n = b / 100;
  int p0 = (b - n * 100) * 256;
  const float* xb = x + (size_t)n * CH * HWL + p0;
  #pragma unroll
  for (int it = 0; it < 8; ++it) {
    int c = it * 4 + (tid >> 6);             // uniform per wave, 1 KB/channel
    dma16(xb + (size_t)c * HWL + (tid & 63) * 4, lds + c * 256);
  }
  __syncthreads();                            // drains vmcnt -> LDS tile ready

  uint32_t bits = 0;
  #pragma unroll
  for (int c = 0; c < 32; ++c) {
    if (lds[c * 256 + tid] > 0.f) bits |= 1u << c;
  }
  int px = p0 + tid;
  int h = px / WW, w = px - h * WW;
  P[n * PIMG + (h + 1) * PRS + (w + 1)] = bits;
}

// ================ K2/K4: conv (recompute) -> per-channel stats only ================
__global__ __launch_bounds__(256) void conv_stats(const uint32_t* __restrict__ P,
    const uint32_t* __restrict__ WP, const int* __restrict__ CORR,
    StatLine* __restrict__ sb)
{
  __shared__ uint32_t wsh[288];
  __shared__ int csh[288];
  __shared__ int ls1[32], ls2[32];
  const int tid = threadIdx.x;
  for (int i = tid; i < 288; i += 256) { wsh[i] = WP[i]; csh[i] = CORR[i]; }
  if (tid < 32) { ls1[tid] = 0; ls2[tid] = 0; }
  __syncthreads();

  int g = blockIdx.x * 256 + tid;
  int w4 = g % 40;
  int t1 = g / 40;
  int h = t1 % 160;
  int n = t1 / 160;

  const uint32_t* base = P + n * PIMG + h * PRS + w4 * 4;
  uint32_t r[3][6];
  #pragma unroll
  for (int dy = 0; dy < 3; ++dy) {
    uint4 a = *reinterpret_cast<const uint4*>(base + dy * PRS);
    uint2 bw = *reinterpret_cast<const uint2*>(base + dy * PRS + 4);
    r[dy][0] = a.x; r[dy][1] = a.y; r[dy][2] = a.z; r[dy][3] = a.w;
    r[dy][4] = bw.x; r[dy][5] = bw.y;
  }

  int rowc = (h == 0) ? 0 : ((h == 159) ? 6 : 3);
  int cls0  = rowc + ((w4 == 0) ? 0 : 1);
  int cls12 = rowc + 1;
  int cls3  = rowc + ((w4 == 39) ? 2 : 1);
  int lane = tid & 63;

  #pragma unroll
  for (int co = 0; co < 32; ++co) {
    int a0, a1, a2, a3;
    conv4(r, wsh, co, a0, a1, a2, a3);
    int d0 = 288 - 2 * a0 - csh[cls0 * 32 + co];
    int d1 = 288 - 2 * a1 - csh[cls12 * 32 + co];
    int d2 = 288 - 2 * a2 - csh[cls12 * 32 + co];
    int d3 = 288 - 2 * a3 - csh[cls3 * 32 + co];
    int ds = d0 + d1 + d2 + d3;
    int sq = d0 * d0 + d1 * d1 + d2 * d2 + d3 * d3;
    #pragma unroll
    for (int off = 32; off > 0; off >>= 1) {
      ds += __shfl_down(ds, off);
      sq += __shfl_down(sq, off);
    }
    if (lane == 0) { atomicAdd(&ls1[co], ds); atomicAdd(&ls2[co], sq); }
  }
  __syncthreads();
  if (tid < 32) {
    atomicAdd(&sb[tid].s1, ls1[tid]);
    atomicAdd(&sb[tid].s2, (unsigned long long)(long long)ls2[tid]);
  }
}

// ================ K3: conv1 + BN1 + residual(x) -> P2 sign bits ONLY ===============
__global__ __launch_bounds__(256, 2) void conv_bn1(const uint32_t* __restrict__ P,
    const uint32_t* __restrict__ WP, const int* __restrict__ CORR,
    const float* __restrict__ x, const float* __restrict__ SCp,
    const StatLine* __restrict__ sb, const float* __restrict__ gamma,
    const float* __restrict__ beta, uint32_t* __restrict__ P2)
{
  __shared__ uint32_t wsh[288];
  __shared__ int csh[288];
  __shared__ float Ash[32], Bsh[32];
  const int tid = threadIdx.x;
  for (int i = tid; i < 288; i += 256) { wsh[i] = WP[i]; csh[i] = CORR[i]; }
  if (tid < 32) {
    double sc = (double)SCp[0];
    double m  = sc * (double)sb[tid].s1 / (double)NPIX;
    double ms = sc * sc * (double)(long long)sb[tid].s2 / (double)NPIX;
    float inv = (float)(1.0 / sqrt(ms - m * m + 1e-5));
    float gm = gamma[tid];
    Ash[tid] = gm * inv * (float)sc;
    Bsh[tid] = beta[tid] - gm * inv * (float)m;
  }
  __syncthreads();

  int g = blockIdx.x * 256 + tid;
  int w4 = g % 40;
  int t1 = g / 40;
  int h = t1 % 160;
  int n = t1 / 160;

  const uint32_t* base = P + n * PIMG + h * PRS + w4 * 4;
  uint32_t r[3][6];
  #pragma unroll
  for (int dy = 0; dy < 3; ++dy) {
    uint4 a = *reinterpret_cast<const uint4*>(base + dy * PRS);
    uint2 bw = *reinterpret_cast<const uint2*>(base + dy * PRS + 4);
    r[dy][0] = a.x; r[dy][1] = a.y; r[dy][2] = a.z; r[dy][3] = a.w;
    r[dy][4] = bw.x; r[dy][5] = bw.y;
  }
  int rowc = (h == 0) ? 0 : ((h == 159) ? 6 : 3);
  int cls0  = rowc + ((w4 == 0) ? 0 : 1);
  int cls12 = rowc + 1;
  int cls3  = rowc + ((w4 == 39) ? 2 : 1);

  int i = h * WW + w4 * 4;
  size_t pbase = (size_t)n * CH * HWL + i;

  uint32_t bb0 = 0, bb1 = 0, bb2 = 0, bb3 = 0;
  #pragma unroll
  for (int cg = 0; cg < 4; ++cg) {
    float4 xv[8];
    #pragma unroll
    for (int j = 0; j < 8; ++j)
      xv[j] = *reinterpret_cast<const float4*>(x + pbase + (size_t)(cg * 8 + j) * HWL);
    #pragma unroll
    for (int j = 0; j < 8; ++j) {
      int co = cg * 8 + j;
      int a0, a1, a2, a3;
      conv4(r, wsh, co, a0, a1, a2, a3);
      int d0 = 288 - 2 * a0 - csh[cls0 * 32 + co];
      int d1 = 288 - 2 * a1 - csh[cls12 * 32 + co];
      int d2 = 288 - 2 * a2 - csh[cls12 * 32 + co];
      int d3 = 288 - 2 * a3 - csh[cls3 * 32 + co];
      float A = Ash[co], Bv = Bsh[co];
      float v0 = fmaf(A, (float)d0, Bv) + xv[j].x;
      float v1 = fmaf(A, (float)d1, Bv) + xv[j].y;
      float v2 = fmaf(A, (float)d2, Bv) + xv[j].z;
      float v3 = fmaf(A, (float)d3, Bv) + xv[j].w;
      uint32_t m = 1u << co;
      if (v0 > 0.f) bb0 |= m;
      if (v1 > 0.f) bb1 |= m;
      if (v2 > 0.f) bb2 |= m;
      if (v3 > 0.f) bb3 |= m;
    }
  }
  uint32_t* pw = P2 + n * PIMG + (h + 1) * PRS + (w4 * 4 + 1);
  pw[0] = bb0; pw[1] = bb1; pw[2] = bb2; pw[3] = bb3;
}

// ================ K5: conv1+conv2 recompute + BN1+BN2 + residual -> out fp32 =======
// out = A2*d2 + B2 + (A1*d1 + B1 + x); inner recomputed exactly, never stored
__global__ __launch_bounds__(256, 2) void conv_bn2(const uint32_t* __restrict__ P,
    const uint32_t* __restrict__ P2, const uint32_t* __restrict__ WP,
    const int* __restrict__ CORR, const float* __restrict__ x,
    const float* __restrict__ SC, const StatLine* __restrict__ SB,
    const float* __restrict__ g1v, const float* __restrict__ b1v,
    const float* __restrict__ g2v, const float* __restrict__ b2v,
    float* __restrict__ out)
{
  __shared__ uint32_t wsh[576];              // both layers' packed weights
  __shared__ int csh[576];
  __shared__ float A1s[32], B1s[32], A2s[32], B2s[32];
  const int tid = threadIdx.x;
  for (int i = tid; i < 576; i += 256) { wsh[i] = WP[i]; csh[i] = CORR[i]; }
  if (tid < 32) {
    double sc = (double)SC[0];
    double m  = sc * (double)SB[tid].s1 / (double)NPIX;
    double ms = sc * sc * (double)(long long)SB[tid].s2 / (double)NPIX;
    float inv = (float)(1.0 / sqrt(ms - m * m + 1e-5));
    float gm = g1v[tid];
    A1s[tid] = gm * inv * (float)sc;
    B1s[tid] = b1v[tid] - gm * inv * (float)m;
    double sc2 = (double)SC[1];
    double m2  = sc2 * (double)SB[32 + tid].s1 / (double)NPIX;
    double ms2 = sc2 * sc2 * (double)(long long)SB[32 + tid].s2 / (double)NPIX;
    float inv2 = (float)(1.0 / sqrt(ms2 - m2 * m2 + 1e-5));
    float gm2 = g2v[tid];
    A2s[tid] = gm2 * inv2 * (float)sc2;
    B2s[tid] = b2v[tid] - gm2 * inv2 * (float)m2;
  }
  __syncthreads();

  int g = blockIdx.x * 256 + tid;
  int w4 = g % 40;
  int t1 = g / 40;
  int h = t1 % 160;
  int n = t1 / 160;

  uint32_t r1[3][6], r2[3][6];
  {
    const uint32_t* b1p = P  + n * PIMG + h * PRS + w4 * 4;
    const uint32_t* b2p = P2 + n * PIMG + h * PRS + w4 * 4;
    #pragma unroll
    for (int dy = 0; dy < 3; ++dy) {
      uint4 a = *reinterpret_cast<const uint4*>(b1p + dy * PRS);
      uint2 bw = *reinterpret_cast<const uint2*>(b1p + dy * PRS + 4);
      r1[dy][0] = a.x; r1[dy][1] = a.y; r1[dy][2] = a.z; r1[dy][3] = a.w;
      r1[dy][4] = bw.x; r1[dy][5] = bw.y;
      uint4 c = *reinterpret_cast<const uint4*>(b2p + dy * PRS);
      uint2 dw = *reinterpret_cast<const uint2*>(b2p + dy * PRS + 4);
      r2[dy][0] = c.x; r2[dy][1] = c.y; r2[dy][2] = c.z; r2[dy][3] = c.w;
      r2[dy][4] = dw.x; r2[dy][5] = dw.y;
    }
  }
  int rowc = (h == 0) ? 0 : ((h == 159) ? 6 : 3);
  int cls0  = rowc + ((w4 == 0) ? 0 : 1);
  int cls12 = rowc + 1;
  int cls3  = rowc + ((w4 == 39) ? 2 : 1);

  int i = h * WW + w4 * 4;
  size_t pbase = (size_t)n * CH * HWL + i;

  #pragma unroll
  for (int cg = 0; cg < 4; ++cg) {
    float4 xv[8];
    #pragma unroll
    for (int j = 0; j < 8; ++j)
      xv[j] = *reinterpret_cast<const float4*>(x + pbase + (size_t)(cg * 8 + j) * HWL);
    #pragma unroll
    for (int j = 0; j < 8; ++j) {
      int co = cg * 8 + j;
      int a0, a1, a2, a3, e0, e1, e2, e3;
      conv4(r1, wsh, co, a0, a1, a2, a3);
      conv4(r2, wsh + 288, co, e0, e1, e2, e3);
      int d0 = 288 - 2 * a0 - csh[cls0 * 32 + co];
      int d1 = 288 - 2 * a1 - csh[cls12 * 32 + co];
      int d2 = 288 - 2 * a2 - csh[cls12 * 32 + co];
      int d3 = 288 - 2 * a3 - csh[cls3 * 32 + co];
      int f0 = 288 - 2 * e0 - csh[288 + cls0 * 32 + co];
      int f1 = 288 - 2 * e1 - csh[288 + cls12 * 32 + co];
      int f2 = 288 - 2 * e2 - csh[288 + cls12 * 32 + co];
      int f3 = 288 - 2 * e3 - csh[288 + cls3 * 32 + co];
      float A1 = A1s[co], B1 = B1s[co], A2 = A2s[co], B2 = B2s[co];
      float v0 = fmaf(A1, (float)d0, B1) + xv[j].x;   // inner, exact fp32
      float v1 = fmaf(A1, (float)d1, B1) + xv[j].y;
      float v2 = fmaf(A1, (float)d2, B1) + xv[j].z;
      float v3 = fmaf(A1, (float)d3, B1) + xv[j].w;
      float4 o;
      o.x = fmaf(A2, (float)f0, B2) + v0;
      o.y = fmaf(A2, (float)f1, B2) + v1;
      o.z = fmaf(A2, (float)f2, B2) + v2;
      o.w = fmaf(A2, (float)f3, B2) + v3;
      *reinterpret_cast<float4*>(out + pbase + (size_t)co * HWL) = o;
    }
  }
}

extern "C" void kernel_launch(void* const* d_in, const int* in_sizes, int n_in,
                              void* d_out, int out_size, void* d_ws, size_t ws_size,
                              hipStream_t stream)
{
  (void)in_sizes; (void)n_in; (void)out_size; (void)ws_size;
  const float* x  = (const float*)d_in[0];
  const float* w1 = (const float*)d_in[1];
  const float* g1 = (const float*)d_in[2];
  const float* b1 = (const float*)d_in[3];
  const float* w2 = (const float*)d_in[4];
  const float* g2 = (const float*)d_in[5];
  const float* b2 = (const float*)d_in[6];
  float* out = (float*)d_out;
  char* ws = (char*)d_ws;

  uint32_t* P    = (uint32_t*)(ws + OFF_P);
  uint32_t* P2   = (uint32_t*)(ws + OFF_P2);
  uint32_t* WP   = (uint32_t*)(ws + OFF_WP);
  int*      CORR = (int*)(ws + OFF_CORR);
  float*    SC   = (float*)(ws + OFF_SC);
  StatLine* SB   = (StatLine*)(ws + OFF_SB);

  pack_prep<<<3443, 256, 0, stream>>>(x, w1, w2, P, P2, WP, CORR, SC, SB);
  conv_stats<<<800, 256, 0, stream>>>(P, WP, CORR, SB);
  conv_bn1<<<800, 256, 0, stream>>>(P, WP, CORR, x, SC, SB, g1, b1, P2);
  conv_stats<<<800, 256, 0, stream>>>(P2, WP + 288, CORR + 288, SB + 32);
  conv_bn2<<<800, 256, 0, stream>>>(P, P2, WP, CORR, x, SC, SB, g1, b1, g2, b2, out);
}